// Round 1
// 345.395 us; speedup vs baseline: 1.2195x; 1.2195x over previous
//
#include <hip/hip_runtime.h>
#include <math.h>

#define SEQ   4096
#define DM    2048
#define NH    16
#define NKV   4
#define HD    128
#define QKVN  3072
// SCALE * log2(e) folded into wq at transpose time: exp(s/sqrt(128)) == exp2(q'.k)
#define CEXP  0.12753643f

typedef _Float16 f16;
typedef _Float16 f16x8 __attribute__((ext_vector_type(8)));
typedef _Float16 f16x4v __attribute__((ext_vector_type(4)));
typedef float    f32x4 __attribute__((ext_vector_type(4)));

// async global->LDS, 16 B/lane. LDS dest is wave-uniform base + lane*16.
#define GLD16(g, l) __builtin_amdgcn_global_load_lds(                        \
    (const __attribute__((address_space(1))) unsigned int*)(g),              \
    (__attribute__((address_space(3))) unsigned int*)(l), 16, 0, 0)

// ---------------------------------------------------------------------------
// fp32 -> fp16 cast, 4 elems/thread
// ---------------------------------------------------------------------------
__global__ __launch_bounds__(256) void cast_f32_f16_k(const float* __restrict__ in,
                                                      f16* __restrict__ out, int n4)
{
    int i = blockIdx.x * 256 + threadIdx.x;
    if (i >= n4) return;
    float4 v = ((const float4*)in)[i];
    f16x4v h = {(f16)v.x, (f16)v.y, (f16)v.z, (f16)v.w};
    ((f16x4v*)out)[i] = h;
}

// ---------------------------------------------------------------------------
// W[R][Cn] fp32 -> Wt[Cn][R] fp16, scaled.  (grid: (Cn/32, R/32))
// ---------------------------------------------------------------------------
__global__ __launch_bounds__(256) void transpose_cast_k(const float* __restrict__ in,
                                                        f16* __restrict__ out,
                                                        int R, int Cn, float scale)
{
    __shared__ float tile[32][33];
    int bx = blockIdx.x * 32, by = blockIdx.y * 32;
    int tx = threadIdx.x & 31, ty = threadIdx.x >> 5;
    #pragma unroll
    for (int i = 0; i < 32; i += 8)
        tile[ty + i][tx] = in[(size_t)(by + ty + i) * Cn + bx + tx];
    __syncthreads();
    #pragma unroll
    for (int i = 0; i < 32; i += 8)
        out[(size_t)(bx + ty + i) * R + by + tx] = (f16)(tile[tx][ty + i] * scale);
}

// ---------------------------------------------------------------------------
// in[R][Cn] fp16 (ld=ldin) -> out[Cn][R] fp16   (grid: (Cn/32, R/32))
// ---------------------------------------------------------------------------
__global__ __launch_bounds__(256) void transpose_f16_k(const f16* __restrict__ in,
                                                       f16* __restrict__ out,
                                                       int R, int Cn, int ldin)
{
    __shared__ f16 tile[32][33];
    int bx = blockIdx.x * 32, by = blockIdx.y * 32;
    int tx = threadIdx.x & 31, ty = threadIdx.x >> 5;
    #pragma unroll
    for (int i = 0; i < 32; i += 8)
        tile[ty + i][tx] = in[(size_t)(by + ty + i) * ldin + bx + tx];
    __syncthreads();
    #pragma unroll
    for (int i = 0; i < 32; i += 8)
        out[(size_t)(bx + ty + i) * R + by + tx] = tile[tx][ty + i];
}

// ---------------------------------------------------------------------------
// C[M][N] = A[M][K] * Bt[N][K]^T, fp16 in / OutT out, fp32 accum.
// 128x128 tile, BK=64, 256 threads = 4 waves (2x2, each wave 64x64 = 4x4 MFMA).
// ---------------------------------------------------------------------------
template <typename OutT>
__global__ __launch_bounds__(256) void gemm_bt(const f16* __restrict__ A,
                                               const f16* __restrict__ Bt,
                                               OutT* __restrict__ C,
                                               int M, int N, int K)
{
    __shared__ __align__(16) f16 sm[16384];      // As[128][64] | Bs[128][64]
    f16* As = sm;
    f16* Bs = sm + 8192;

    const int t = threadIdx.x;
    const int w = t >> 6;
    const int lane = t & 63, ln = lane & 15, quad = lane >> 4;
    const size_t bm = (size_t)blockIdx.y * 128, bn = (size_t)blockIdx.x * 128;
    const int wm = (w >> 1) * 64, wn = (w & 1) * 64;

    int srow[4], scol[4];
    #pragma unroll
    for (int cc = 0; cc < 4; ++cc) {
        int pos = cc * 256 + t;
        srow[cc] = pos >> 3;
        scol[cc] = ((pos & 7) ^ (srow[cc] & 7)) * 8;
    }

    f32x4 acc[4][4];
    #pragma unroll
    for (int i = 0; i < 4; ++i)
        #pragma unroll
        for (int j = 0; j < 4; ++j) acc[i][j] = (f32x4){0.f, 0.f, 0.f, 0.f};

    for (int k0 = 0; k0 < K; k0 += 64) {
        #pragma unroll
        for (int cc = 0; cc < 4; ++cc) {
            GLD16(A  + (bm + srow[cc]) * (size_t)K + k0 + scol[cc],
                  As + (cc * 256 + w * 64) * 8);
            GLD16(Bt + (bn + srow[cc]) * (size_t)K + k0 + scol[cc],
                  Bs + (cc * 256 + w * 64) * 8);
        }
        __syncthreads();

        #pragma unroll
        for (int tt = 0; tt < 2; ++tt) {
            const int ch = ((tt * 4 + quad) ^ (ln & 7)) * 8;
            f16x8 af[4], bf[4];
            #pragma unroll
            for (int i = 0; i < 4; ++i) {
                af[i] = *(const f16x8*)&As[(wm + i * 16 + ln) * 64 + ch];
                bf[i] = *(const f16x8*)&Bs[(wn + i * 16 + ln) * 64 + ch];
            }
            #pragma unroll
            for (int i = 0; i < 4; ++i)
                #pragma unroll
                for (int j = 0; j < 4; ++j)
                    acc[i][j] = __builtin_amdgcn_mfma_f32_16x16x32_f16(af[i], bf[j], acc[i][j], 0, 0, 0);
        }
        __syncthreads();
    }

    #pragma unroll
    for (int i = 0; i < 4; ++i)
        #pragma unroll
        for (int j = 0; j < 4; ++j)
            #pragma unroll
            for (int r = 0; r < 4; ++r)
                C[(bm + wm + i * 16 + quad * 4 + r) * (size_t)N + bn + wn + j * 16 + ln]
                    = (OutT)acc[i][j][r];
}

// ---------------------------------------------------------------------------
// RoPE in place on qkv fp16: q cols [0,2048), k cols [2048,2560). fp32 math.
// inv_freq = 10000^(-2i/128) = exp2(-i * log2(1e4)/64) — one exp2, no powf.
// ---------------------------------------------------------------------------
__global__ __launch_bounds__(256) void rope_k(f16* __restrict__ qkv)
{
    const int s = blockIdx.x, t = threadIdx.x;
    for (int p = t; p < (NH + NKV) * 64; p += 256) {
        int hh = p >> 6, i = p & 63;
        f16* base = (hh < NH) ? qkv + (size_t)s * QKVN + hh * HD
                              : qkv + (size_t)s * QKVN + DM + (hh - NH) * HD;
        float inv = __builtin_exp2f((float)i * -0.20762050f);
        float ang = (float)s * inv;
        float c = cosf(ang), sn = sinf(ang);
        float x0 = (float)base[i], x1 = (float)base[i + 64];
        base[i]      = (f16)(x0 * c - x1 * sn);
        base[i + 64] = (f16)(x1 * c + x0 * sn);
    }
}

// ---------------------------------------------------------------------------
// Split-K flash attention, fp16 MFMA, fixed-max softmax.
// ROUND 7: restructured for pipe utilization (was MfmaUtil 15%, 190 us):
//  * 256 threads = 4 waves, q-tile 128 rows (each wave keeps the proven
//    32-row fragment/softmax/PV code). K/V staging amortized over 2x rows:
//    total LDS-fill traffic 1.06 GB -> 0.53 GB.
//  * K/V DOUBLE-BUFFERED with prefetch: issue next tile's GLD16 BEFORE
//    computing current tile; single __syncthreads at loop bottom drains
//    loads that had the whole compute phase to land (T3 pattern). The old
//    stage->drain->compute order exposed full L2/L3 latency every tile.
//    One barrier per tile instead of two.
//  * XCD-local KV: h decoded from blockIdx.x so each XCD (bid%8 round-robin)
//    serves one kv-head -> 2 MB K+V slice stays L2-resident (was: all 16 MB
//    of KV thrashing every XCD's 4 MB L2).
//  * Pair (px, 31-px) + 33/33 split-K: every block exactly 33 KV tiles.
// LDS = 2*16K (K dbuf) + 2*16K (V dbuf) + 16K (P, 4 KB/wave) = 81920 B
// -> exactly 2 blocks/CU of the 160 KiB pool; grid 512 = exactly 2/CU.
// Fixed-max softmax => partials over disjoint KV ranges merge by addition.
// Empty sub-ranges store zeros so all (row, half) slots are covered.
// ---------------------------------------------------------------------------
__global__ __launch_bounds__(256, 2) void flash_k(const f16* __restrict__ qkv,
                                                  const f16* __restrict__ vt,
                                                  f16* __restrict__ O0,
                                                  f16* __restrict__ O1,
                                                  float* __restrict__ lpart)
{
    // XCD-local decode (assumes XCD = linear block id % 8, round-robin).
    const int bid  = blockIdx.x;            // 0..511
    const int xcd  = bid & 7;
    const int rr   = bid >> 3;              // 0..63
    const int kvh  = xcd >> 1;              // XCD pair -> one kv head
    const int h    = kvh * 4 + (xcd & 1) * 2 + (rr & 1);
    const int px   = (rr >> 1) & 15;        // 0..15
    const int half = rr >> 5;               // 0..1

    const int t = threadIdx.x, w = t >> 6, lane = t & 63, ln = lane & 15, quad = lane >> 4;

    f16*   Op = half ? O1 : O0;
    float* lp = lpart + (size_t)half * NH * SEQ + (size_t)h * SEQ;

    __shared__ __align__(16) f16 sm[40960];  // 81920 B
    // Ks[buf]  = sm + buf*8192          : [64][128], chunk-swizzled ^(row&15)
    // Vts[buf] = sm + 16384 + buf*8192  : [128][64], chunk-swizzled ^(row&7)
    f16* Ps = sm + 32768 + w * 2048;     // per-wave [32][64], chunk-swizzled ^(row&7)

    const int glo = half * 33;           // linear tile range [glo, ghi), 33 each
    const int ghi = glo + 33;

    // fixed per-thread staging geometry
    int krow[4], kc[4], vrow[4], vc[4];
    #pragma unroll
    for (int cc = 0; cc < 4; ++cc) {
        int pos = cc * 256 + t;
        krow[cc] = pos >> 4; kc[cc] = (pos & 15) ^ (krow[cc] & 15);
        vrow[cc] = pos >> 3; vc[cc] = (pos & 7) ^ (vrow[cc] & 7);
    }

    #pragma unroll
    for (int ph = 0; ph < 2; ++ph) {
        const int bx   = ph ? (31 - px) : px;
        const int q0   = bx * 128;
        const int ntp  = 2 * bx + 2;              // KV tiles for this q-tile
        const int base = ph ? (2 * px + 2) : 0;   // linear offset of phase
        int tb_lo = glo - base; if (tb_lo < 0) tb_lo = 0;
        int tb_hi = ghi - base; if (tb_hi > ntp) tb_hi = ntp;

        // incrementally-advanced staging source pointers (start at tb_lo)
        const f16* kp[4]; const f16* vp[4];
        #pragma unroll
        for (int cc = 0; cc < 4; ++cc) {
            kp[cc] = qkv + (size_t)(tb_lo * 64 + krow[cc]) * QKVN + DM + kvh * HD + kc[cc] * 8;
            vp[cc] = vt  + (size_t)(kvh * HD + vrow[cc]) * SEQ + tb_lo * 64 + vc[cc] * 8;
        }
        auto stage = [&](int b) {
            f16* Kd = sm + b * 8192;
            f16* Vd = sm + 16384 + b * 8192;
            #pragma unroll
            for (int cc = 0; cc < 4; ++cc) {
                GLD16(kp[cc], Kd + (cc * 256 + t) * 8);
                GLD16(vp[cc], Vd + (cc * 256 + t) * 8);
                kp[cc] += 64 * QKVN;
                vp[cc] += 64;
            }
        };

        // Q fragments to registers: rows q0 + w*32 + rf*16 + ln
        f16x8 qf[2][4];
        #pragma unroll
        for (int rf = 0; rf < 2; ++rf) {
            const f16* qrow = qkv + (size_t)(q0 + w * 32 + rf * 16 + ln) * QKVN + h * HD;
            #pragma unroll
            for (int tt = 0; tt < 4; ++tt)
                qf[rf][tt] = *(const f16x8*)(qrow + tt * 32 + quad * 8);
        }

        float l_r[2][4] = {{0.f, 0.f, 0.f, 0.f}, {0.f, 0.f, 0.f, 0.f}};
        f32x4 oacc[2][8];
        #pragma unroll
        for (int rf = 0; rf < 2; ++rf)
            #pragma unroll
            for (int dt = 0; dt < 8; ++dt) oacc[rf][dt] = (f32x4){0.f, 0.f, 0.f, 0.f};

        if (tb_lo < tb_hi) stage(0);     // prologue stage (uniform condition)
        __syncthreads();                 // buf0 ready

        for (int tb = tb_lo; tb < tb_hi; ++tb) {
            const int cur = (tb - tb_lo) & 1;
            if (tb + 1 < tb_hi) stage(cur ^ 1);   // async prefetch next tile

            const f16* Ks  = sm + cur * 8192;
            const f16* Vts = sm + 16384 + cur * 8192;

            // ---- S = Q K^T : each bk read feeds both row-frags ----
            f32x4 sacc[2][4];
            #pragma unroll
            for (int rf = 0; rf < 2; ++rf)
                #pragma unroll
                for (int c2 = 0; c2 < 4; ++c2) sacc[rf][c2] = (f32x4){0.f, 0.f, 0.f, 0.f};
            #pragma unroll
            for (int tt = 0; tt < 4; ++tt) {
                #pragma unroll
                for (int c2 = 0; c2 < 4; ++c2) {
                    f16x8 bk = *(const f16x8*)&Ks[(c2 * 16 + ln) * 128 + ((tt * 4 + quad) ^ ln) * 8];
                    sacc[0][c2] = __builtin_amdgcn_mfma_f32_16x16x32_f16(qf[0][tt], bk, sacc[0][c2], 0, 0, 0);
                    sacc[1][c2] = __builtin_amdgcn_mfma_f32_16x16x32_f16(qf[1][tt], bk, sacc[1][c2], 0, 0, 0);
                }
            }

            // ---- mask on the two diagonal tiles (uniform branch) ----
            if (tb >= ntp - 2) {
                const int ko = (tb - (ntp - 2)) * 64;   // 0 or 64, kv offset vs q0
                #pragma unroll
                for (int rf = 0; rf < 2; ++rf)
                    #pragma unroll
                    for (int c2 = 0; c2 < 4; ++c2)
                        #pragma unroll
                        for (int r = 0; r < 4; ++r)
                            if (ko + c2 * 16 + ln > w * 32 + rf * 16 + quad * 4 + r)
                                sacc[rf][c2][r] = -INFINITY;
            }

            // ---- p = exp2(s) (scale pre-folded) ----
            #pragma unroll
            for (int rf = 0; rf < 2; ++rf)
                #pragma unroll
                for (int c2 = 0; c2 < 4; ++c2)
                    #pragma unroll
                    for (int r = 0; r < 4; ++r) {
                        float e = __builtin_exp2f(sacc[rf][c2][r]);
                        l_r[rf][r] += e;
                        int row = rf * 16 + quad * 4 + r;
                        int slot = (c2 * 2 + (ln >> 3)) ^ (row & 7);
                        Ps[row * 64 + slot * 8 + (ln & 7)] = (f16)e;
                    }
            // no barrier: Ps is per-wave; lgkmcnt orders write->read

            // ---- O += P @ V : each bv read feeds both row-frags ----
            #pragma unroll
            for (int t2 = 0; t2 < 2; ++t2) {
                f16x8 pa0 = *(const f16x8*)&Ps[(0 * 16 + ln) * 64 + ((t2 * 4 + quad) ^ (ln & 7)) * 8];
                f16x8 pa1 = *(const f16x8*)&Ps[(1 * 16 + ln) * 64 + ((t2 * 4 + quad) ^ (ln & 7)) * 8];
                #pragma unroll
                for (int dt = 0; dt < 8; ++dt) {
                    f16x8 bv = *(const f16x8*)&Vts[(dt * 16 + ln) * 64 + ((t2 * 4 + quad) ^ (ln & 7)) * 8];
                    oacc[0][dt] = __builtin_amdgcn_mfma_f32_16x16x32_f16(pa0, bv, oacc[0][dt], 0, 0, 0);
                    oacc[1][dt] = __builtin_amdgcn_mfma_f32_16x16x32_f16(pa1, bv, oacc[1][dt], 0, 0, 0);
                }
            }

            __syncthreads();   // drains prefetch (overlapped with compute above)
                               // + all waves done reading buf[cur]
        }

        // ---- per-row l sum over 16 lanes; store UNNORMALIZED partials ----
        #pragma unroll
        for (int rf = 0; rf < 2; ++rf)
            #pragma unroll
            for (int r = 0; r < 4; ++r) {
                float l = l_r[rf][r];
                l += __shfl_xor(l, 1, 64);
                l += __shfl_xor(l, 2, 64);
                l += __shfl_xor(l, 4, 64);
                l += __shfl_xor(l, 8, 64);
                if (ln == 0)
                    lp[q0 + w * 32 + rf * 16 + quad * 4 + r] = l;
            }
        #pragma unroll
        for (int rf = 0; rf < 2; ++rf)
            #pragma unroll
            for (int dt = 0; dt < 8; ++dt)
                #pragma unroll
                for (int r = 0; r < 4; ++r)
                    Op[(size_t)(q0 + w * 32 + rf * 16 + quad * 4 + r) * DM + h * HD + dt * 16 + ln]
                        = (f16)oacc[rf][dt][r];
    }
}

// ---------------------------------------------------------------------------
// merge: oh = (O0 + O1) / (l0 + l1). oh aliases O0 (same-index in-thread RW).
// ---------------------------------------------------------------------------
__global__ __launch_bounds__(256) void merge_k(const f16* __restrict__ O0,
                                               const f16* __restrict__ O1,
                                               const float* __restrict__ l0,
                                               const float* __restrict__ l1,
                                               f16* __restrict__ oh)
{
    int idx = blockIdx.x * 256 + threadIdx.x;      // vector id, 1M total
    int row = idx >> 8;                            // 256 f16x8 vectors per row
    int hh  = (idx & 255) >> 4;                    // 16 vectors per head
    float li = 1.0f / (l0[hh * SEQ + row] + l1[hh * SEQ + row]);
    f16x8 a = ((const f16x8*)O0)[idx];
    f16x8 b = ((const f16x8*)O1)[idx];
    f16x8 o;
    #pragma unroll
    for (int i = 0; i < 8; ++i)
        o[i] = (f16)(((float)a[i] + (float)b[i]) * li);
    ((f16x8*)oh)[idx] = o;
}

// ---------------------------------------------------------------------------
extern "C" void kernel_launch(void* const* d_in, const int* in_sizes, int n_in,
                              void* d_out, int out_size, void* d_ws, size_t ws_size,
                              hipStream_t stream)
{
    (void)in_sizes; (void)n_in; (void)out_size; (void)ws_size;
    const float* x  = (const float*)d_in[0];
    const float* wq = (const float*)d_in[1];
    const float* wk = (const float*)d_in[2];
    const float* wv = (const float*)d_in[3];
    const float* wo = (const float*)d_in[4];
    float* out = (float*)d_out;

    // Layout (f16 elems) — total 41,943,040 f16 = 83,886,080 B, exactly the
    // footprint round 1 proved safe for this harness's ws_size.
    f16* xh    = (f16*)d_ws;                    //  8,388,608  [4096][2048]
    f16* wtqkv = xh + 8388608ull;               //  6,291,456  [3072][2048]
    f16* wot   = wtqkv + 6291456ull;            //  4,194,304  [2048][2048]
    f16* qkvb  = wot + 4194304ull;              // 12,582,912  [4096][3072]
    f16* vtb   = qkvb + 12582912ull;            //  2,097,152  [512][4096]
    f16* O1    = vtb + 2097152ull;              //  8,388,608  [4096][2048] partial
    f16* O0    = xh;     // reuse: xh dead after gemm_qkv
    f16* oh    = xh;     // merge writes in place over O0 (same-index, safe)
    float* lbuf = (float*)wtqkv;  // 131,072 f32; wtqkv dead after gemm_qkv

    cast_f32_f16_k<<<8192, 256, 0, stream>>>(x, xh, 2097152);
    transpose_cast_k<<<dim3(64, 64), 256, 0, stream>>>(wq, wtqkv, 2048, 2048, CEXP);
    transpose_cast_k<<<dim3(16, 64), 256, 0, stream>>>(wk, wtqkv + 2048ull * 2048, 2048, 512, 1.0f);
    transpose_cast_k<<<dim3(16, 64), 256, 0, stream>>>(wv, wtqkv + 2560ull * 2048, 2048, 512, 1.0f);
    transpose_cast_k<<<dim3(64, 64), 256, 0, stream>>>(wo, wot, 2048, 2048, 1.0f);

    gemm_bt<f16><<<dim3(24, 32), 256, 0, stream>>>(xh, wtqkv, qkvb, 4096, 3072, 2048);
    rope_k<<<4096, 256, 0, stream>>>(qkvb);
    transpose_f16_k<<<dim3(16, 128), 256, 0, stream>>>(qkvb + 2560, vtb, 4096, 512, 3072);
    flash_k<<<dim3(512), 256, 0, stream>>>(qkvb, vtb, O0, O1, lbuf);
    merge_k<<<4096, 256, 0, stream>>>(O0, O1, lbuf, lbuf + (size_t)NH * SEQ, oh);
    gemm_bt<float><<<dim3(16, 32), 256, 0, stream>>>(oh, wot, out, 4096, 2048, 2048);
}

// Round 3
// 327.595 us; speedup vs baseline: 1.2857x; 1.0543x over previous
//
#include <hip/hip_runtime.h>
#include <math.h>

#define SEQ   4096
#define DM    2048
#define NH    16
#define NKV   4
#define HD    128
#define QKVN  3072
// SCALE * log2(e) folded into wq at transpose time: exp(s/sqrt(128)) == exp2(q'.k)
#define CEXP  0.12753643f

typedef _Float16 f16;
typedef _Float16 f16x8 __attribute__((ext_vector_type(8)));
typedef _Float16 f16x4v __attribute__((ext_vector_type(4)));
typedef float    f32x4 __attribute__((ext_vector_type(4)));

// async global->LDS, 16 B/lane. LDS dest is wave-uniform base + lane*16.
#define GLD16(g, l) __builtin_amdgcn_global_load_lds(                        \
    (const __attribute__((address_space(1))) unsigned int*)(g),              \
    (__attribute__((address_space(3))) unsigned int*)(l), 16, 0, 0)

// ---------------------------------------------------------------------------
// fp32 -> fp16 cast, 4 elems/thread
// ---------------------------------------------------------------------------
__global__ __launch_bounds__(256) void cast_f32_f16_k(const float* __restrict__ in,
                                                      f16* __restrict__ out, int n4)
{
    int i = blockIdx.x * 256 + threadIdx.x;
    if (i >= n4) return;
    float4 v = ((const float4*)in)[i];
    f16x4v h = {(f16)v.x, (f16)v.y, (f16)v.z, (f16)v.w};
    ((f16x4v*)out)[i] = h;
}

// ---------------------------------------------------------------------------
// W[R][Cn] fp32 -> Wt[Cn][R] fp16, scaled.  (grid: (Cn/32, R/32))
// ---------------------------------------------------------------------------
__global__ __launch_bounds__(256) void transpose_cast_k(const float* __restrict__ in,
                                                        f16* __restrict__ out,
                                                        int R, int Cn, float scale)
{
    __shared__ float tile[32][33];
    int bx = blockIdx.x * 32, by = blockIdx.y * 32;
    int tx = threadIdx.x & 31, ty = threadIdx.x >> 5;
    #pragma unroll
    for (int i = 0; i < 32; i += 8)
        tile[ty + i][tx] = in[(size_t)(by + ty + i) * Cn + bx + tx];
    __syncthreads();
    #pragma unroll
    for (int i = 0; i < 32; i += 8)
        out[(size_t)(bx + ty + i) * R + by + tx] = (f16)(tile[tx][ty + i] * scale);
}

// ---------------------------------------------------------------------------
// in[R][Cn] fp16 (ld=ldin) -> out[Cn][R] fp16   (grid: (Cn/32, R/32))
// ---------------------------------------------------------------------------
__global__ __launch_bounds__(256) void transpose_f16_k(const f16* __restrict__ in,
                                                       f16* __restrict__ out,
                                                       int R, int Cn, int ldin)
{
    __shared__ f16 tile[32][33];
    int bx = blockIdx.x * 32, by = blockIdx.y * 32;
    int tx = threadIdx.x & 31, ty = threadIdx.x >> 5;
    #pragma unroll
    for (int i = 0; i < 32; i += 8)
        tile[ty + i][tx] = in[(size_t)(by + ty + i) * ldin + bx + tx];
    __syncthreads();
    #pragma unroll
    for (int i = 0; i < 32; i += 8)
        out[(size_t)(bx + ty + i) * R + by + tx] = tile[tx][ty + i];
}

// ---------------------------------------------------------------------------
// ROUND 8 (retry of round-7 submission after container failure; hardened):
// phase-interleaved counted-vmcnt GEMM (T2+T3+T4+T5 stack).
// C[M][N] = A[M][K] * Bt[N][K]^T, fp16 in / OutT out, fp32 accum.
// BM=256 x BN(256|128) tile, BK=64, 512 threads = 8 waves, wave grid 8M x 1N:
// wave w owns C rows [w*32, w*32+32), all BN cols -> acc 2 x (BN/16) frags.
//
// Phase structure (4 phases per K-tile; phase q computes n-chunk q = B rows
// [q*BN/4, (q+1)*BN/4) over full BK=64):
//   { ds_read B-frags (+A-frags at q0) | stage ONE half-tile of K-tile t+1
//     | counted vmcnt | ONE barrier | setprio(1) MFMAs setprio(0) }
// (Round-7 had a second barrier after the MFMAs; it is provably redundant:
//  every LDS read of a buffer precedes the mid-barrier of its phase, and the
//  cross-tile buffer-swap WAR hazard is closed by the LAST reading phase's
//  mid-barrier. Removing it halves raw-barrier count: 4/K-tile.)
//
// Counted-vmcnt correctness (LA=2 loads/A-half, LB=2|1 loads/B-half per thr):
//   stage order per K-tile t: P1:A0' P2:A1' P3:B0' P4:B1'  (' = t+1)
//   consumption: A-frags ds_read only at P1; B-half0 read P1-P2,
//   B-half1 read P3-P4 (n-chunk order == staging order).
//   vmcnt(4)@P2: outstanding {B1(t):LB, A0':2, A1':2} -> drains B1(t)
//     => B-half1(t) landed before every wave passes P2's barrier, ahead of
//        its P3/P4 reads.  (kt=0: B1(0) already drained in prologue; no-op.)
//   vmcnt(LB)@P4: outstanding {A0':2, A1':2, B0':LB, B1':LB} -> leaves only
//     B1' => A0',A1',B0' landed before any wave passes P4's barrier, ahead
//     of tile t+1's P1/P2 reads. Never drains to 0; 2-8 loads in flight.
// Raw s_barrier (no implicit vmcnt-0 drain); "memory"-clobber asm pins
// GLD/ds ops against the counted waits; sched_barrier(0) pins phase shape.
// LDS: A 2x32K + B 2x(BN*128B) = 128 KiB (BN=256) / 96 KiB (BN=128) -> 1 blk/CU.
// ---------------------------------------------------------------------------
template <int BN, typename OutT>
__global__ __launch_bounds__(512, 2) void gemm8p(const f16* __restrict__ A,
                                                 const f16* __restrict__ Bt,
                                                 OutT* __restrict__ C,
                                                 int M, int N, int K)
{
    constexpr int LB  = (BN == 256) ? 2 : 1;   // GLD16s per B half-stage per thread
    constexpr int NF  = BN / 16;               // n-frags per wave (16 | 8)
    constexpr int NPP = NF / 4;                // n-frags per phase (4 | 2)
    (void)M;

    __shared__ __align__(16) f16 sm[32768 + 2 * BN * 64];
    f16* As = sm;                  // [2][256][64], chunk-swizzled ^(row&7)
    f16* Bs = sm + 32768;          // [2][BN][64],  chunk-swizzled ^(row&7)

    const int t = threadIdx.x;
    const int w = t >> 6;                       // wave 0..7
    const int lane = t & 63, ln = lane & 15, quad = lane >> 4;
    const size_t bm = (size_t)blockIdx.y * 256, bn = (size_t)blockIdx.x * BN;

    auto stageA = [&](int half, int nb, size_t kn) {
        #pragma unroll
        for (int cc = 0; cc < 2; ++cc) {
            int pos = cc * 512 + t;             // 128 rows x 8 chunks
            int rl  = pos >> 3;
            int sc  = (pos & 7) ^ (rl & 7);
            GLD16(A + (bm + half * 128 + rl) * (size_t)K + kn + sc * 8,
                  As + nb * 16384 + half * 8192 + pos * 8);
        }
    };
    auto stageB = [&](int half, int nb, size_t kn) {
        #pragma unroll
        for (int cc = 0; cc < LB; ++cc) {
            int pos = cc * 512 + t;             // (BN/2) rows x 8 chunks
            int rl  = pos >> 3;
            int sc  = (pos & 7) ^ (rl & 7);
            GLD16(Bt + (bn + half * (BN / 2) + rl) * (size_t)K + kn + sc * 8,
                  Bs + nb * (BN * 64) + half * (BN * 32) + pos * 8);
        }
    };

    f32x4 acc[2][NF];
    #pragma unroll
    for (int i = 0; i < 2; ++i)
        #pragma unroll
        for (int j = 0; j < NF; ++j) acc[i][j] = (f32x4){0.f, 0.f, 0.f, 0.f};

    const int KT = K >> 6;

    // prologue: K-tile 0 -> buf 0, full drain once
    stageA(0, 0, 0); stageA(1, 0, 0); stageB(0, 0, 0); stageB(1, 0, 0);
    asm volatile("s_waitcnt vmcnt(0)" ::: "memory");
    __builtin_amdgcn_s_barrier();

    f16x8 af[2][2];

    for (int kt = 0; kt < KT; ++kt) {
        const int b = kt & 1, nb = b ^ 1;
        // clamped next-tile k offset: last iteration harmlessly re-stages
        // tile KT-1 into the dead buffer, keeping vmcnt counts uniform.
        const size_t kn = (size_t)((kt + 1 < KT) ? (kt + 1) * 64 : (KT - 1) * 64);
        const int Ab = b * 16384, Bb = b * (BN * 64);

        #pragma unroll
        for (int q = 0; q < 4; ++q) {
            if (q == 0) {                       // A-frags, reused all 4 phases
                #pragma unroll
                for (int i = 0; i < 2; ++i)
                    #pragma unroll
                    for (int kk = 0; kk < 2; ++kk)
                        af[i][kk] = *(const f16x8*)&As[Ab + (w * 32 + i * 16 + ln) * 64
                                                         + ((kk * 4 + quad) ^ (ln & 7)) * 8];
            }
            f16x8 bf[NPP][2];
            #pragma unroll
            for (int jj = 0; jj < NPP; ++jj)
                #pragma unroll
                for (int kk = 0; kk < 2; ++kk)
                    bf[jj][kk] = *(const f16x8*)&Bs[Bb + ((q * NPP + jj) * 16 + ln) * 64
                                                       + ((kk * 4 + quad) ^ (ln & 7)) * 8];

            if (q == 0) stageA(0, nb, kn);
            if (q == 1) stageA(1, nb, kn);
            if (q == 2) stageB(0, nb, kn);
            if (q == 3) stageB(1, nb, kn);

            if (q == 1) asm volatile("s_waitcnt vmcnt(4)" ::: "memory");
            if (q == 3) {
                if constexpr (LB == 2) asm volatile("s_waitcnt vmcnt(2)" ::: "memory");
                else                   asm volatile("s_waitcnt vmcnt(1)" ::: "memory");
            }

            __builtin_amdgcn_sched_barrier(0);
            __builtin_amdgcn_s_barrier();
            __builtin_amdgcn_sched_barrier(0);
            __builtin_amdgcn_s_setprio(1);
            #pragma unroll
            for (int jj = 0; jj < NPP; ++jj)
                #pragma unroll
                for (int i = 0; i < 2; ++i)
                    #pragma unroll
                    for (int kk = 0; kk < 2; ++kk)
                        acc[i][q * NPP + jj] = __builtin_amdgcn_mfma_f32_16x16x32_f16(
                            af[i][kk], bf[jj][kk], acc[i][q * NPP + jj], 0, 0, 0);
            __builtin_amdgcn_s_setprio(0);
            __builtin_amdgcn_sched_barrier(0);
        }
    }

    #pragma unroll
    for (int i = 0; i < 2; ++i)
        #pragma unroll
        for (int j = 0; j < NF; ++j)
            #pragma unroll
            for (int r = 0; r < 4; ++r)
                C[(bm + w * 32 + i * 16 + quad * 4 + r) * (size_t)N + bn + j * 16 + ln]
                    = (OutT)acc[i][j][r];
}

// ---------------------------------------------------------------------------
// RoPE in place on qkv fp16: q cols [0,2048), k cols [2048,2560). fp32 math.
// inv_freq = 10000^(-2i/128) = exp2(-i * log2(1e4)/64) — one exp2, no powf.
// ---------------------------------------------------------------------------
__global__ __launch_bounds__(256) void rope_k(f16* __restrict__ qkv)
{
    const int s = blockIdx.x, t = threadIdx.x;
    for (int p = t; p < (NH + NKV) * 64; p += 256) {
        int hh = p >> 6, i = p & 63;
        f16* base = (hh < NH) ? qkv + (size_t)s * QKVN + hh * HD
                              : qkv + (size_t)s * QKVN + DM + (hh - NH) * HD;
        float inv = __builtin_exp2f((float)i * -0.20762050f);
        float ang = (float)s * inv;
        float c = cosf(ang), sn = sinf(ang);
        float x0 = (float)base[i], x1 = (float)base[i + 64];
        base[i]      = (f16)(x0 * c - x1 * sn);
        base[i + 64] = (f16)(x1 * c + x0 * sn);
    }
}

// ---------------------------------------------------------------------------
// Split-K flash attention, fp16 MFMA, fixed-max softmax. (unchanged from the
// round-1 PASS: 4 waves / q-tile 128 / K,V double-buffered prefetch /
// XCD-local KV.)  LDS = 81920 B -> 2 blocks/CU; grid 512 = exactly 2/CU.
// Fixed-max softmax => partials over disjoint KV ranges merge by addition.
// ---------------------------------------------------------------------------
__global__ __launch_bounds__(256, 2) void flash_k(const f16* __restrict__ qkv,
                                                  const f16* __restrict__ vt,
                                                  f16* __restrict__ O0,
                                                  f16* __restrict__ O1,
                                                  float* __restrict__ lpart)
{
    // XCD-local decode (assumes XCD = linear block id % 8, round-robin).
    const int bid  = blockIdx.x;            // 0..511
    const int xcd  = bid & 7;
    const int rr   = bid >> 3;              // 0..63
    const int kvh  = xcd >> 1;              // XCD pair -> one kv head
    const int h    = kvh * 4 + (xcd & 1) * 2 + (rr & 1);
    const int px   = (rr >> 1) & 15;        // 0..15
    const int half = rr >> 5;               // 0..1

    const int t = threadIdx.x, w = t >> 6, lane = t & 63, ln = lane & 15, quad = lane >> 4;

    f16*   Op = half ? O1 : O0;
    float* lp = lpart + (size_t)half * NH * SEQ + (size_t)h * SEQ;

    __shared__ __align__(16) f16 sm[40960];  // 81920 B
    // Ks[buf]  = sm + buf*8192          : [64][128], chunk-swizzled ^(row&15)
    // Vts[buf] = sm + 16384 + buf*8192  : [128][64], chunk-swizzled ^(row&7)
    f16* Ps = sm + 32768 + w * 2048;     // per-wave [32][64], chunk-swizzled ^(row&7)

    const int glo = half * 33;           // linear tile range [glo, ghi), 33 each
    const int ghi = glo + 33;

    // fixed per-thread staging geometry
    int krow[4], kc[4], vrow[4], vc[4];
    #pragma unroll
    for (int cc = 0; cc < 4; ++cc) {
        int pos = cc * 256 + t;
        krow[cc] = pos >> 4; kc[cc] = (pos & 15) ^ (krow[cc] & 15);
        vrow[cc] = pos >> 3; vc[cc] = (pos & 7) ^ (vrow[cc] & 7);
    }

    #pragma unroll
    for (int ph = 0; ph < 2; ++ph) {
        const int bx   = ph ? (31 - px) : px;
        const int q0   = bx * 128;
        const int ntp  = 2 * bx + 2;              // KV tiles for this q-tile
        const int base = ph ? (2 * px + 2) : 0;   // linear offset of phase
        int tb_lo = glo - base; if (tb_lo < 0) tb_lo = 0;
        int tb_hi = ghi - base; if (tb_hi > ntp) tb_hi = ntp;

        // incrementally-advanced staging source pointers (start at tb_lo)
        const f16* kp[4]; const f16* vp[4];
        #pragma unroll
        for (int cc = 0; cc < 4; ++cc) {
            kp[cc] = qkv + (size_t)(tb_lo * 64 + krow[cc]) * QKVN + DM + kvh * HD + kc[cc] * 8;
            vp[cc] = vt  + (size_t)(kvh * HD + vrow[cc]) * SEQ + tb_lo * 64 + vc[cc] * 8;
        }
        auto stage = [&](int b) {
            f16* Kd = sm + b * 8192;
            f16* Vd = sm + 16384 + b * 8192;
            #pragma unroll
            for (int cc = 0; cc < 4; ++cc) {
                GLD16(kp[cc], Kd + (cc * 256 + t) * 8);
                GLD16(vp[cc], Vd + (cc * 256 + t) * 8);
                kp[cc] += 64 * QKVN;
                vp[cc] += 64;
            }
        };

        // Q fragments to registers: rows q0 + w*32 + rf*16 + ln
        f16x8 qf[2][4];
        #pragma unroll
        for (int rf = 0; rf < 2; ++rf) {
            const f16* qrow = qkv + (size_t)(q0 + w * 32 + rf * 16 + ln) * QKVN + h * HD;
            #pragma unroll
            for (int tt = 0; tt < 4; ++tt)
                qf[rf][tt] = *(const f16x8*)(qrow + tt * 32 + quad * 8);
        }

        float l_r[2][4] = {{0.f, 0.f, 0.f, 0.f}, {0.f, 0.f, 0.f, 0.f}};
        f32x4 oacc[2][8];
        #pragma unroll
        for (int rf = 0; rf < 2; ++rf)
            #pragma unroll
            for (int dt = 0; dt < 8; ++dt) oacc[rf][dt] = (f32x4){0.f, 0.f, 0.f, 0.f};

        if (tb_lo < tb_hi) stage(0);     // prologue stage (uniform condition)
        __syncthreads();                 // buf0 ready

        for (int tb = tb_lo; tb < tb_hi; ++tb) {
            const int cur = (tb - tb_lo) & 1;
            if (tb + 1 < tb_hi) stage(cur ^ 1);   // async prefetch next tile

            const f16* Ks  = sm + cur * 8192;
            const f16* Vts = sm + 16384 + cur * 8192;

            // ---- S = Q K^T : each bk read feeds both row-frags ----
            f32x4 sacc[2][4];
            #pragma unroll
            for (int rf = 0; rf < 2; ++rf)
                #pragma unroll
                for (int c2 = 0; c2 < 4; ++c2) sacc[rf][c2] = (f32x4){0.f, 0.f, 0.f, 0.f};
            #pragma unroll
            for (int tt = 0; tt < 4; ++tt) {
                #pragma unroll
                for (int c2 = 0; c2 < 4; ++c2) {
                    f16x8 bk = *(const f16x8*)&Ks[(c2 * 16 + ln) * 128 + ((tt * 4 + quad) ^ ln) * 8];
                    sacc[0][c2] = __builtin_amdgcn_mfma_f32_16x16x32_f16(qf[0][tt], bk, sacc[0][c2], 0, 0, 0);
                    sacc[1][c2] = __builtin_amdgcn_mfma_f32_16x16x32_f16(qf[1][tt], bk, sacc[1][c2], 0, 0, 0);
                }
            }

            // ---- mask on the two diagonal tiles (uniform branch) ----
            if (tb >= ntp - 2) {
                const int ko = (tb - (ntp - 2)) * 64;   // 0 or 64, kv offset vs q0
                #pragma unroll
                for (int rf = 0; rf < 2; ++rf)
                    #pragma unroll
                    for (int c2 = 0; c2 < 4; ++c2)
                        #pragma unroll
                        for (int r = 0; r < 4; ++r)
                            if (ko + c2 * 16 + ln > w * 32 + rf * 16 + quad * 4 + r)
                                sacc[rf][c2][r] = -INFINITY;
            }

            // ---- p = exp2(s) (scale pre-folded) ----
            #pragma unroll
            for (int rf = 0; rf < 2; ++rf)
                #pragma unroll
                for (int c2 = 0; c2 < 4; ++c2)
                    #pragma unroll
                    for (int r = 0; r < 4; ++r) {
                        float e = __builtin_exp2f(sacc[rf][c2][r]);
                        l_r[rf][r] += e;
                        int row = rf * 16 + quad * 4 + r;
                        int slot = (c2 * 2 + (ln >> 3)) ^ (row & 7);
                        Ps[row * 64 + slot * 8 + (ln & 7)] = (f16)e;
                    }
            // no barrier: Ps is per-wave; lgkmcnt orders write->read

            // ---- O += P @ V : each bv read feeds both row-frags ----
            #pragma unroll
            for (int t2 = 0; t2 < 2; ++t2) {
                f16x8 pa0 = *(const f16x8*)&Ps[(0 * 16 + ln) * 64 + ((t2 * 4 + quad) ^ (ln & 7)) * 8];
                f16x8 pa1 = *(const f16x8*)&Ps[(1 * 16 + ln) * 64 + ((t2 * 4 + quad) ^ (ln & 7)) * 8];
                #pragma unroll
                for (int dt = 0; dt < 8; ++dt) {
                    f16x8 bv = *(const f16x8*)&Vts[(dt * 16 + ln) * 64 + ((t2 * 4 + quad) ^ (ln & 7)) * 8];
                    oacc[0][dt] = __builtin_amdgcn_mfma_f32_16x16x32_f16(pa0, bv, oacc[0][dt], 0, 0, 0);
                    oacc[1][dt] = __builtin_amdgcn_mfma_f32_16x16x32_f16(pa1, bv, oacc[1][dt], 0, 0, 0);
                }
            }

            __syncthreads();   // drains prefetch (overlapped with compute above)
                               // + all waves done reading buf[cur]
        }

        // ---- per-row l sum over 16 lanes; store UNNORMALIZED partials ----
        #pragma unroll
        for (int rf = 0; rf < 2; ++rf)
            #pragma unroll
            for (int r = 0; r < 4; ++r) {
                float l = l_r[rf][r];
                l += __shfl_xor(l, 1, 64);
                l += __shfl_xor(l, 2, 64);
                l += __shfl_xor(l, 4, 64);
                l += __shfl_xor(l, 8, 64);
                if (ln == 0)
                    lp[q0 + w * 32 + rf * 16 + quad * 4 + r] = l;
            }
        #pragma unroll
        for (int rf = 0; rf < 2; ++rf)
            #pragma unroll
            for (int dt = 0; dt < 8; ++dt)
                #pragma unroll
                for (int r = 0; r < 4; ++r)
                    Op[(size_t)(q0 + w * 32 + rf * 16 + quad * 4 + r) * DM + h * HD + dt * 16 + ln]
                        = (f16)oacc[rf][dt][r];
    }
}

// ---------------------------------------------------------------------------
// merge: oh = (O0 + O1) / (l0 + l1). oh aliases O0 (same-index in-thread RW).
// ---------------------------------------------------------------------------
__global__ __launch_bounds__(256) void merge_k(const f16* __restrict__ O0,
                                               const f16* __restrict__ O1,
                                               const float* __restrict__ l0,
                                               const float* __restrict__ l1,
                                               f16* __restrict__ oh)
{
    int idx = blockIdx.x * 256 + threadIdx.x;      // vector id, 1M total
    int row = idx >> 8;                            // 256 f16x8 vectors per row
    int hh  = (idx & 255) >> 4;                    // 16 vectors per head
    float li = 1.0f / (l0[hh * SEQ + row] + l1[hh * SEQ + row]);
    f16x8 a = ((const f16x8*)O0)[idx];
    f16x8 b = ((const f16x8*)O1)[idx];
    f16x8 o;
    #pragma unroll
    for (int i = 0; i < 8; ++i)
        o[i] = (f16)(((float)a[i] + (float)b[i]) * li);
    ((f16x8*)oh)[idx] = o;
}

// ---------------------------------------------------------------------------
extern "C" void kernel_launch(void* const* d_in, const int* in_sizes, int n_in,
                              void* d_out, int out_size, void* d_ws, size_t ws_size,
                              hipStream_t stream)
{
    (void)in_sizes; (void)n_in; (void)out_size; (void)ws_size;
    const float* x  = (const float*)d_in[0];
    const float* wq = (const float*)d_in[1];
    const float* wk = (const float*)d_in[2];
    const float* wv = (const float*)d_in[3];
    const float* wo = (const float*)d_in[4];
    float* out = (float*)d_out;

    // Layout (f16 elems) — total 41,943,040 f16 = 83,886,080 B, exactly the
    // footprint round 1 proved safe for this harness's ws_size.
    f16* xh    = (f16*)d_ws;                    //  8,388,608  [4096][2048]
    f16* wtqkv = xh + 8388608ull;               //  6,291,456  [3072][2048]
    f16* wot   = wtqkv + 6291456ull;            //  4,194,304  [2048][2048]
    f16* qkvb  = wot + 4194304ull;              // 12,582,912  [4096][3072]
    f16* vtb   = qkvb + 12582912ull;            //  2,097,152  [512][4096]
    f16* O1    = vtb + 2097152ull;              //  8,388,608  [4096][2048] partial
    f16* O0    = xh;     // reuse: xh dead after gemm_qkv
    f16* oh    = xh;     // merge writes in place over O0 (same-index, safe)
    float* lbuf = (float*)wtqkv;  // 131,072 f32; wtqkv dead after gemm_qkv

    cast_f32_f16_k<<<8192, 256, 0, stream>>>(x, xh, 2097152);
    transpose_cast_k<<<dim3(64, 64), 256, 0, stream>>>(wq, wtqkv, 2048, 2048, CEXP);
    transpose_cast_k<<<dim3(16, 64), 256, 0, stream>>>(wk, wtqkv + 2048ull * 2048, 2048, 512, 1.0f);
    transpose_cast_k<<<dim3(16, 64), 256, 0, stream>>>(wv, wtqkv + 2560ull * 2048, 2048, 512, 1.0f);
    transpose_cast_k<<<dim3(64, 64), 256, 0, stream>>>(wo, wot, 2048, 2048, 1.0f);

    gemm8p<256, f16><<<dim3(12, 16), 512, 0, stream>>>(xh, wtqkv, qkvb, 4096, 3072, 2048);
    rope_k<<<4096, 256, 0, stream>>>(qkvb);
    transpose_f16_k<<<dim3(16, 128), 256, 0, stream>>>(qkvb + 2560, vtb, 4096, 512, 3072);
    flash_k<<<dim3(512), 256, 0, stream>>>(qkvb, vtb, O0, O1, lbuf);
    merge_k<<<4096, 256, 0, stream>>>(O0, O1, lbuf, lbuf + (size_t)NH * SEQ, oh);
    gemm8p<128, float><<<dim3(16, 16), 512, 0, stream>>>(oh, wot, out, 4096, 2048, 2048);
}